// Round 10
// baseline (276.184 us; speedup 1.0000x reference)
//
#include <hip/hip_runtime.h>
#include <stdint.h>

typedef __bf16 bf16x8 __attribute__((ext_vector_type(8)));
typedef float f32x4 __attribute__((ext_vector_type(4)));

// Native bf16 conversion (RNE): compiler emits v_cvt_pk_bf16_f32 on gfx950.
__device__ __forceinline__ unsigned short f2bf(float f) {
    union { __bf16 h; unsigned short u; } v;
    v.h = (__bf16)f;
    return v.u;
}

#define QS_STRIDE 40   // q/k 64x32 tiles, +8 pad
#define VT_STRIDE 72   // vT 32x64 tile, +8 pad
#define PS_STRIDE 72   // p 16x64 per-wave strip, +8 pad
#define XH_STRIDE 40   // xh 16x32 per-wave strip, +8 pad

// ---------------- combined precompute kernel ----------------
// blocks [0,6144):  bm[(w*6+h)*4096 + r*64 + c] = mask[w][r][c] + rpb[rpi[r][c]][h]
// blocks [6144,6288): wf[((h*12+ct)*64+lane)*8+e] = bf16(W[ct*16+(lane&15)][h*32+(lane>>4)*8+e])
__global__ void prep_all(const int* __restrict__ rpi32,
                         const float* __restrict__ mask,
                         const float* __restrict__ rpb,
                         const float* __restrict__ proj_w,
                         float* __restrict__ bm,
                         unsigned short* __restrict__ wf) {
    int bid = blockIdx.x;
    int tid = threadIdx.x;
    if (bid < 6144) {
        __shared__ int is64_s;
        if (tid == 0) {
            int s = 0;
            #pragma unroll
            for (int i = 0; i < 16; ++i) s |= rpi32[2 * i + 1];
            is64_s = (s == 0);
        }
        __syncthreads();
        int g = bid * 256 + tid;              // < 64*6*4096
        int wh = g >> 12;                     // w*6+h
        int e  = g & 4095;                    // r*64 + c
        int h = wh % 6, w = wh / 6;
        int rv = is64_s ? rpi32[2 * e] : rpi32[e];
        bm[g] = mask[w * 4096 + e] + rpb[rv * 6 + h];
    } else {
        int g = (bid - 6144) * 256 + tid;     // < 36864
        int e = g & 7;
        int lane = (g >> 3) & 63;
        int kkct = g >> 9;
        int kk = kkct / 12, ct = kkct % 12;
        int co = ct * 16 + (lane & 15);
        int ki = kk * 32 + (lane >> 4) * 8 + e;
        wf[g] = f2bf(proj_w[co * 192 + ki]);
    }
}

// ------ fast fused kernel (R8 pipeline + per-head proj accumulation, 29KB LDS, 4 blk/CU) ------

__global__ __launch_bounds__(256, 4)
void winattn_fast(const float* __restrict__ qkv,
                  const float* __restrict__ bm,
                  const unsigned short* __restrict__ wf,
                  const float* __restrict__ proj_b,
                  float* __restrict__ out) {
    __shared__ __align__(16) unsigned short u_s[7424];                // 14848 B: q|k|vT
    __shared__ __align__(16) unsigned short p_s[4 * 16 * PS_STRIDE];  // 9216 B (own-wave strips)
    __shared__ __align__(16) unsigned short xh_s[4 * 16 * XH_STRIDE]; // 5120 B (own-wave strips)

    unsigned short* q_s  = u_s;          // [64][40]
    unsigned short* k_s  = u_s + 2560;   // [64][40]
    unsigned short* vT_s = u_s + 5120;   // [32][72]

    const int tid  = threadIdx.x;
    const int b    = blockIdx.x;
    const int lane = tid & 63;
    const int wv   = tid >> 6;
    const int l16  = lane & 15;
    const int lhi  = lane >> 4;
    const int qbase = wv * 16;
    const float scale = 0.17677669529663687f;

    const float* qkv_b = qkv + (size_t)b * 64 * 576;
    const float* bm_w  = bm + (size_t)(b & 63) * 6 * 4096;

    // staging geometry: thread covers (tokA, dA) and (tokB = tokA+32, dA)
    const int tokA = tid >> 3;
    const int dA   = (tid & 7) << 2;
    const float4* gA = (const float4*)(qkv_b + tokA * 576 + dA); // head h: +h*8 (f4), k:+48, v:+96
    const float4* gB = (const float4*)(qkv_b + (tokA + 32) * 576 + dA);

    float4 q0, k0, v0, q1, k1, v1;

#define LOADH(h_)  do { int o = (h_) * 8;                         \
        q0 = gA[o];      k0 = gA[o + 48]; v0 = gA[o + 96];        \
        q1 = gB[o];      k1 = gB[o + 48]; v1 = gB[o + 96]; } while (0)

#define STOREH() do {                                             \
        ushort4 qh, kh;                                           \
        qh.x = f2bf(q0.x * scale); qh.y = f2bf(q0.y * scale);     \
        qh.z = f2bf(q0.z * scale); qh.w = f2bf(q0.w * scale);     \
        kh.x = f2bf(k0.x); kh.y = f2bf(k0.y);                     \
        kh.z = f2bf(k0.z); kh.w = f2bf(k0.w);                     \
        *(ushort4*)&q_s[tokA * QS_STRIDE + dA] = qh;              \
        *(ushort4*)&k_s[tokA * QS_STRIDE + dA] = kh;              \
        vT_s[(dA + 0) * VT_STRIDE + tokA] = f2bf(v0.x);           \
        vT_s[(dA + 1) * VT_STRIDE + tokA] = f2bf(v0.y);           \
        vT_s[(dA + 2) * VT_STRIDE + tokA] = f2bf(v0.z);           \
        vT_s[(dA + 3) * VT_STRIDE + tokA] = f2bf(v0.w);           \
        qh.x = f2bf(q1.x * scale); qh.y = f2bf(q1.y * scale);     \
        qh.z = f2bf(q1.z * scale); qh.w = f2bf(q1.w * scale);     \
        kh.x = f2bf(k1.x); kh.y = f2bf(k1.y);                     \
        kh.z = f2bf(k1.z); kh.w = f2bf(k1.w);                     \
        *(ushort4*)&q_s[(tokA + 32) * QS_STRIDE + dA] = qh;       \
        *(ushort4*)&k_s[(tokA + 32) * QS_STRIDE + dA] = kh;       \
        vT_s[(dA + 0) * VT_STRIDE + tokA + 32] = f2bf(v1.x);      \
        vT_s[(dA + 1) * VT_STRIDE + tokA + 32] = f2bf(v1.y);      \
        vT_s[(dA + 2) * VT_STRIDE + tokA + 32] = f2bf(v1.z);      \
        vT_s[(dA + 3) * VT_STRIDE + tokA + 32] = f2bf(v1.w); } while (0)

    LOADH(0);
    STOREH();

    unsigned short* pw = p_s + wv * 16 * PS_STRIDE;
    unsigned short* xh = xh_s + wv * 16 * XH_STRIDE;

    f32x4 oacc[12];
    #pragma unroll
    for (int ct = 0; ct < 12; ++ct) oacc[ct] = (f32x4){0.f, 0.f, 0.f, 0.f};

    for (int h = 0; h < 6; ++h) {
        __syncthreads();                 // A: stage for head h visible
        if (h < 5) LOADH(h + 1);         // issue next head's loads early

        // bias+mask for this wave's 16 q-rows: lane needs bias[q=qbase+l16][k=nt*16+lhi*4+j]
        const float* bmh = bm_w + h * 4096;
        float4 bv[4];
        #pragma unroll
        for (int nt = 0; nt < 4; ++nt)
            bv[nt] = *(const float4*)&bmh[(qbase + l16) * 64 + nt * 16 + lhi * 4];

        // ---------- S^T = K Q^T (swapped: lane l16 holds q-column qbase+l16) ----------
        bf16x8 aq = *(const bf16x8*)&q_s[(qbase + l16) * QS_STRIDE + lhi * 8];
        float lg[4][4];   // lg[nt][j]: S[q=qbase+l16][k=nt*16+lhi*4+j] + bias
        #pragma unroll
        for (int nt = 0; nt < 4; ++nt) {
            bf16x8 bk = *(const bf16x8*)&k_s[(nt * 16 + l16) * QS_STRIDE + lhi * 8];
            f32x4 c = {0.f, 0.f, 0.f, 0.f};
            c = __builtin_amdgcn_mfma_f32_16x16x32_bf16(bk, aq, c, 0, 0, 0); // swapped operands
            lg[nt][0] = c[0] + bv[nt].x; lg[nt][1] = c[1] + bv[nt].y;
            lg[nt][2] = c[2] + bv[nt].z; lg[nt][3] = c[3] + bv[nt].w;
        }

        // ---------- lane-local softmax: 16 local values + 2-lane-hop reduce ----------
        float m = lg[0][0];
        #pragma unroll
        for (int nt = 0; nt < 4; ++nt)
            #pragma unroll
            for (int j = 0; j < 4; ++j) m = fmaxf(m, lg[nt][j]);
        m = fmaxf(m, __shfl_xor(m, 16, 64));
        m = fmaxf(m, __shfl_xor(m, 32, 64));
        float s = 0.f;
        #pragma unroll
        for (int nt = 0; nt < 4; ++nt)
            #pragma unroll
            for (int j = 0; j < 4; ++j) { lg[nt][j] = __expf(lg[nt][j] - m); s += lg[nt][j]; }
        s += __shfl_xor(s, 16, 64);
        s += __shfl_xor(s, 32, 64);
        float inv = __builtin_amdgcn_rcpf(s);

        // P (pre-normalized) -> own-wave strip: 4x packed ushort4, row q=l16
        #pragma unroll
        for (int nt = 0; nt < 4; ++nt) {
            ushort4 ph;
            ph.x = f2bf(lg[nt][0] * inv); ph.y = f2bf(lg[nt][1] * inv);
            ph.z = f2bf(lg[nt][2] * inv); ph.w = f2bf(lg[nt][3] * inv);
            *(ushort4*)&pw[l16 * PS_STRIDE + nt * 16 + lhi * 4] = ph;
        }

        // ---------- X_h = P V ----------
        f32x4 xo[2] = {{0.f,0.f,0.f,0.f},{0.f,0.f,0.f,0.f}};
        #pragma unroll
        for (int kk = 0; kk < 2; ++kk) {
            bf16x8 pa = *(const bf16x8*)&pw[l16 * PS_STRIDE + kk * 32 + lhi * 8];
            #pragma unroll
            for (int dt = 0; dt < 2; ++dt) {
                bf16x8 vb = *(const bf16x8*)&vT_s[(dt * 16 + l16) * VT_STRIDE + kk * 32 + lhi * 8];
                xo[dt] = __builtin_amdgcn_mfma_f32_16x16x32_bf16(pa, vb, xo[dt], 0, 0, 0);
            }
        }
        // X_h (C-layout: row q=qbase+lhi*4+j, col d=dt*16+l16) -> own-wave strip (A-layout)
        #pragma unroll
        for (int j = 0; j < 4; ++j) {
            #pragma unroll
            for (int dt = 0; dt < 2; ++dt)
                xh[(lhi * 4 + j) * XH_STRIDE + dt * 16 + l16] = f2bf(xo[dt][j]);
        }

        // ---------- per-head proj accumulation: oacc += X_h @ W[:, h*32:+32]^T ----------
        bf16x8 ax = *(const bf16x8*)&xh[l16 * XH_STRIDE + lhi * 8];
        #pragma unroll
        for (int ct = 0; ct < 12; ++ct) {
            bf16x8 bw = *(const bf16x8*)&wf[((h * 12 + ct) * 64 + lane) * 8];
            oacc[ct] = __builtin_amdgcn_mfma_f32_16x16x32_bf16(ax, bw, oacc[ct], 0, 0, 0);
        }

        __syncthreads();                 // B: all waves done reading q/k/vT
        if (h < 5) STOREH();             // write next head's stage
    }
#undef LOADH
#undef STOREH

    float* outb = out + (size_t)b * 64 * 192;
    #pragma unroll
    for (int ct = 0; ct < 12; ++ct) {
        int co = ct * 16 + l16;
        float bias = proj_b[co];
        #pragma unroll
        for (int j = 0; j < 4; ++j) {
            int n = qbase + lhi * 4 + j;
            outb[n * 192 + co] = oacc[ct][j] + bias;
        }
    }
}

// ---------------- fallback (self-contained, used if ws too small) ----------------

#define XS_STRIDE 200
#define WS_STRIDE 40

__global__ __launch_bounds__(256)
void winattn_fused(const float* __restrict__ qkv,
                   const int* __restrict__ rpi32,
                   const float* __restrict__ mask,
                   const float* __restrict__ rpb_table,
                   const float* __restrict__ proj_w,
                   const float* __restrict__ proj_b,
                   float* __restrict__ out) {
    __shared__ __align__(16) unsigned short x_s[64 * XS_STRIDE];
    __shared__ __align__(16) unsigned short u_s[12032];
    __shared__ float rpb_s[225];
    __shared__ int rpi_is64_s;

    unsigned short* q_s  = u_s;
    unsigned short* k_s  = u_s + 2560;
    unsigned short* vT_s = u_s + 5120;
    unsigned short* p_s  = u_s + 7424;
    unsigned short* w_s  = u_s;

    const int tid  = threadIdx.x;
    const int b    = blockIdx.x;
    const int lane = tid & 63;
    const int wv   = tid >> 6;
    const int l16  = lane & 15;
    const int lhi  = lane >> 4;
    const int qbase = wv * 16;
    const float scale = 0.17677669529663687f;

    if (tid == 0) {
        int s = 0;
        #pragma unroll
        for (int i = 0; i < 16; ++i) s |= rpi32[2 * i + 1];
        rpi_is64_s = (s == 0) ? 1 : 0;
    }

    const float* maskw = mask + (size_t)(b & 63) * 4096;
    const float* qkv_b = qkv + (size_t)b * 64 * 576;

    for (int h = 0; h < 6; ++h) {
        for (int idx = tid; idx < 64 * 8; idx += 256) {
            int tok = idx >> 3, d = (idx & 7) << 2;
            const float4* base = (const float4*)(qkv_b + tok * 576 + h * 32 + d);
            float4 qv = base[0];
            float4 kv = base[48];
            float4 vv = base[96];
            ushort4 qh, kh;
            qh.x = f2bf(qv.x * scale); qh.y = f2bf(qv.y * scale);
            qh.z = f2bf(qv.z * scale); qh.w = f2bf(qv.w * scale);
            kh.x = f2bf(kv.x); kh.y = f2bf(kv.y); kh.z = f2bf(kv.z); kh.w = f2bf(kv.w);
            *(ushort4*)&q_s[tok * QS_STRIDE + d] = qh;
            *(ushort4*)&k_s[tok * QS_STRIDE + d] = kh;
            vT_s[(d + 0) * VT_STRIDE + tok] = f2bf(vv.x);
            vT_s[(d + 1) * VT_STRIDE + tok] = f2bf(vv.y);
            vT_s[(d + 2) * VT_STRIDE + tok] = f2bf(vv.z);
            vT_s[(d + 3) * VT_STRIDE + tok] = f2bf(vv.w);
        }
        if (tid < 225) rpb_s[tid] = rpb_table[tid * 6 + h];
        __syncthreads();
        const int is64 = rpi_is64_s;

        bf16x8 aq = *(const bf16x8*)&q_s[(qbase + l16) * QS_STRIDE + lhi * 8];
        float lg[4][4];
        #pragma unroll
        for (int nt = 0; nt < 4; ++nt) {
            bf16x8 bk = *(const bf16x8*)&k_s[(nt * 16 + l16) * QS_STRIDE + lhi * 8];
            f32x4 c = {0.f, 0.f, 0.f, 0.f};
            c = __builtin_amdgcn_mfma_f32_16x16x32_bf16(aq, bk, c, 0, 0, 0);
            #pragma unroll
            for (int j = 0; j < 4; ++j) lg[nt][j] = c[j];
        }
        #pragma unroll
        for (int nt = 0; nt < 4; ++nt) {
            int c = nt * 16 + l16;
            #pragma unroll
            for (int j = 0; j < 4; ++j) {
                int r = qbase + lhi * 4 + j;
                int e = r * 64 + c;
                int rv = is64 ? rpi32[2 * e] : rpi32[e];
                lg[nt][j] += rpb_s[rv] + maskw[e];
            }
        }
        float srow[4];
        float p[4][4];
        #pragma unroll
        for (int j = 0; j < 4; ++j) {
            float m = fmaxf(fmaxf(lg[0][j], lg[1][j]), fmaxf(lg[2][j], lg[3][j]));
            #pragma unroll
            for (int o = 1; o < 16; o <<= 1) m = fmaxf(m, __shfl_xor(m, o, 64));
            float s = 0.f;
            #pragma unroll
            for (int nt = 0; nt < 4; ++nt) { p[nt][j] = __expf(lg[nt][j] - m); s += p[nt][j]; }
            #pragma unroll
            for (int o = 1; o < 16; o <<= 1) s += __shfl_xor(s, o, 64);
            srow[j] = s;
        }
        __syncthreads();
        unsigned short* pw = p_s + wv * 16 * PS_STRIDE;
        #pragma unroll
        for (int nt = 0; nt < 4; ++nt)
            #pragma unroll
            for (int j = 0; j < 4; ++j)
                pw[(lhi * 4 + j) * PS_STRIDE + nt * 16 + l16] = f2bf(p[nt][j]);
        __syncthreads();

        f32x4 xo[2] = {{0.f,0.f,0.f,0.f},{0.f,0.f,0.f,0.f}};
        #pragma unroll
        for (int kk = 0; kk < 2; ++kk) {
            bf16x8 pa = *(const bf16x8*)&pw[l16 * PS_STRIDE + kk * 32 + lhi * 8];
            #pragma unroll
            for (int dt = 0; dt < 2; ++dt) {
                bf16x8 vb = *(const bf16x8*)&vT_s[(dt * 16 + l16) * VT_STRIDE + kk * 32 + lhi * 8];
                xo[dt] = __builtin_amdgcn_mfma_f32_16x16x32_bf16(pa, vb, xo[dt], 0, 0, 0);
            }
        }
        #pragma unroll
        for (int j = 0; j < 4; ++j) {
            float inv = 1.f / srow[j];
            int n = qbase + lhi * 4 + j;
            #pragma unroll
            for (int dt = 0; dt < 2; ++dt)
                x_s[n * XS_STRIDE + h * 32 + dt * 16 + l16] = f2bf(xo[dt][j] * inv);
        }
        __syncthreads();
    }

    f32x4 oacc[12];
    #pragma unroll
    for (int ct = 0; ct < 12; ++ct) oacc[ct] = (f32x4){0.f, 0.f, 0.f, 0.f};
    for (int kk = 0; kk < 6; ++kk) {
        for (int idx = tid; idx < 192 * 8; idx += 256) {
            int co = idx >> 3, d = (idx & 7) << 2;
            float4 wvv = *(const float4*)(proj_w + co * 192 + kk * 32 + d);
            ushort4 wh;
            wh.x = f2bf(wvv.x); wh.y = f2bf(wvv.y); wh.z = f2bf(wvv.z); wh.w = f2bf(wvv.w);
            *(ushort4*)&w_s[co * WS_STRIDE + d] = wh;
        }
        __syncthreads();
        bf16x8 ax = *(const bf16x8*)&x_s[(qbase + l16) * XS_STRIDE + kk * 32 + lhi * 8];
        #pragma unroll
        for (int ct = 0; ct < 12; ++ct) {
            bf16x8 bw = *(const bf16x8*)&w_s[(ct * 16 + l16) * WS_STRIDE + lhi * 8];
            oacc[ct] = __builtin_amdgcn_mfma_f32_16x16x32_bf16(ax, bw, oacc[ct], 0, 0, 0);
        }
        __syncthreads();
    }
    float* outb = out + (size_t)b * 64 * 192;
    #pragma unroll
    for (int ct = 0; ct < 12; ++ct) {
        int co = ct * 16 + l16;
        float bias = proj_b[co];
        #pragma unroll
        for (int j = 0; j < 4; ++j) {
            int n = qbase + lhi * 4 + j;
            outb[n * 192 + co] = oacc[ct][j] + bias;
        }
    }
}

extern "C" void kernel_launch(void* const* d_in, const int* in_sizes, int n_in,
                              void* d_out, int out_size, void* d_ws, size_t ws_size,
                              hipStream_t stream) {
    (void)in_sizes; (void)n_in; (void)out_size;
    const float* qkv       = (const float*)d_in[0];
    const int*   rpi       = (const int*)d_in[1];
    const float* mask      = (const float*)d_in[2];
    const float* rpb_table = (const float*)d_in[3];
    const float* proj_w    = (const float*)d_in[4];
    const float* proj_b    = (const float*)d_in[5];
    float* out = (float*)d_out;

    const size_t BM_BYTES = (size_t)64 * 6 * 4096 * sizeof(float);   // 6,291,456
    const size_t WF_BYTES = (size_t)36864 * sizeof(unsigned short);  // 73,728

    if (ws_size >= BM_BYTES + WF_BYTES) {
        float* bmp = (float*)d_ws;
        unsigned short* wfp = (unsigned short*)((char*)d_ws + BM_BYTES);
        prep_all<<<6144 + 144, 256, 0, stream>>>(rpi, mask, rpb_table, proj_w, bmp, wfp);
        winattn_fast<<<4096, 256, 0, stream>>>(qkv, bmp, wfp, proj_b, out);
    } else {
        winattn_fused<<<4096, 256, 0, stream>>>(qkv, rpi, mask, rpb_table, proj_w, proj_b, out);
    }
}

// Round 11
// 204.347 us; speedup vs baseline: 1.3515x; 1.3515x over previous
//
#include <hip/hip_runtime.h>
#include <stdint.h>

typedef __bf16 bf16x8 __attribute__((ext_vector_type(8)));
typedef float f32x4 __attribute__((ext_vector_type(4)));

// Native bf16 conversion (RNE): compiler emits v_cvt_pk_bf16_f32 on gfx950.
__device__ __forceinline__ unsigned short f2bf(float f) {
    union { __bf16 h; unsigned short u; } v;
    v.h = (__bf16)f;
    return v.u;
}

#define QS_STRIDE 40   // q/k 64x32 tiles, +8 pad
#define VT_STRIDE 72   // vT 32x64 tile, +8 pad
#define PS_STRIDE 72   // p 16x64 per-wave strip, +8 pad
#define XH_STRIDE 40   // xh 16x32 per-wave strip, +8 pad

// ---------------- combined precompute kernel ----------------
// blocks [0,6144):  bm[(w*6+h)*4096 + r*64 + c] = mask[w][r][c] + rpb[rpi[r][c]][h]
// blocks [6144,6288): wf[((h*12+ct)*64+lane)*8+e] = bf16(W[ct*16+(lane&15)][h*32+(lane>>4)*8+e])
__global__ void prep_all(const int* __restrict__ rpi32,
                         const float* __restrict__ mask,
                         const float* __restrict__ rpb,
                         const float* __restrict__ proj_w,
                         float* __restrict__ bm,
                         unsigned short* __restrict__ wf) {
    int bid = blockIdx.x;
    int tid = threadIdx.x;
    if (bid < 6144) {
        __shared__ int is64_s;
        if (tid == 0) {
            int s = 0;
            #pragma unroll
            for (int i = 0; i < 16; ++i) s |= rpi32[2 * i + 1];
            is64_s = (s == 0);
        }
        __syncthreads();
        int g = bid * 256 + tid;              // < 64*6*4096
        int wh = g >> 12;                     // w*6+h
        int e  = g & 4095;                    // r*64 + c
        int h = wh % 6, w = wh / 6;
        int rv = is64_s ? rpi32[2 * e] : rpi32[e];
        bm[g] = mask[w * 4096 + e] + rpb[rv * 6 + h];
    } else {
        int g = (bid - 6144) * 256 + tid;     // < 36864
        int e = g & 7;
        int lane = (g >> 3) & 63;
        int kkct = g >> 9;
        int kk = kkct / 12, ct = kkct % 12;
        int co = ct * 16 + (lane & 15);
        int ki = kk * 32 + (lane >> 4) * 8 + e;
        wf[g] = f2bf(proj_w[co * 192 + ki]);
    }
}

// ------ fast fused kernel: R8 pipeline + X carried in regs (ax0..ax5), end-proj, 29KB LDS ------

__global__ __launch_bounds__(256, 4)
void winattn_fast(const float* __restrict__ qkv,
                  const float* __restrict__ bm,
                  const unsigned short* __restrict__ wf,
                  const float* __restrict__ proj_b,
                  float* __restrict__ out) {
    __shared__ __align__(16) unsigned short u_s[7424];                // 14848 B: q|k|vT
    __shared__ __align__(16) unsigned short p_s[4 * 16 * PS_STRIDE];  // 9216 B (own-wave strips)
    __shared__ __align__(16) unsigned short xh_s[4 * 16 * XH_STRIDE]; // 5120 B (own-wave strips)

    unsigned short* q_s  = u_s;          // [64][40]
    unsigned short* k_s  = u_s + 2560;   // [64][40]
    unsigned short* vT_s = u_s + 5120;   // [32][72]

    const int tid  = threadIdx.x;
    const int b    = blockIdx.x;
    const int lane = tid & 63;
    const int wv   = tid >> 6;
    const int l16  = lane & 15;
    const int lhi  = lane >> 4;
    const int qbase = wv * 16;
    const float scale = 0.17677669529663687f;

    const float* qkv_b = qkv + (size_t)b * 64 * 576;
    const float* bm_w  = bm + (size_t)(b & 63) * 6 * 4096;

    // staging geometry: thread covers (tokA, dA) and (tokB = tokA+32, dA)
    const int tokA = tid >> 3;
    const int dA   = (tid & 7) << 2;
    const float4* gA = (const float4*)(qkv_b + tokA * 576 + dA); // head h: +h*8 (f4), k:+48, v:+96
    const float4* gB = (const float4*)(qkv_b + (tokA + 32) * 576 + dA);

    float4 q0, k0, v0, q1, k1, v1;

#define LOADH(h_)  do { int o = (h_) * 8;                         \
        q0 = gA[o];      k0 = gA[o + 48]; v0 = gA[o + 96];        \
        q1 = gB[o];      k1 = gB[o + 48]; v1 = gB[o + 96]; } while (0)

#define STOREH() do {                                             \
        ushort4 qh, kh;                                           \
        qh.x = f2bf(q0.x * scale); qh.y = f2bf(q0.y * scale);     \
        qh.z = f2bf(q0.z * scale); qh.w = f2bf(q0.w * scale);     \
        kh.x = f2bf(k0.x); kh.y = f2bf(k0.y);                     \
        kh.z = f2bf(k0.z); kh.w = f2bf(k0.w);                     \
        *(ushort4*)&q_s[tokA * QS_STRIDE + dA] = qh;              \
        *(ushort4*)&k_s[tokA * QS_STRIDE + dA] = kh;              \
        vT_s[(dA + 0) * VT_STRIDE + tokA] = f2bf(v0.x);           \
        vT_s[(dA + 1) * VT_STRIDE + tokA] = f2bf(v0.y);           \
        vT_s[(dA + 2) * VT_STRIDE + tokA] = f2bf(v0.z);           \
        vT_s[(dA + 3) * VT_STRIDE + tokA] = f2bf(v0.w);           \
        qh.x = f2bf(q1.x * scale); qh.y = f2bf(q1.y * scale);     \
        qh.z = f2bf(q1.z * scale); qh.w = f2bf(q1.w * scale);     \
        kh.x = f2bf(k1.x); kh.y = f2bf(k1.y);                     \
        kh.z = f2bf(k1.z); kh.w = f2bf(k1.w);                     \
        *(ushort4*)&q_s[(tokA + 32) * QS_STRIDE + dA] = qh;       \
        *(ushort4*)&k_s[(tokA + 32) * QS_STRIDE + dA] = kh;       \
        vT_s[(dA + 0) * VT_STRIDE + tokA + 32] = f2bf(v1.x);      \
        vT_s[(dA + 1) * VT_STRIDE + tokA + 32] = f2bf(v1.y);      \
        vT_s[(dA + 2) * VT_STRIDE + tokA + 32] = f2bf(v1.z);      \
        vT_s[(dA + 3) * VT_STRIDE + tokA + 32] = f2bf(v1.w); } while (0)

    LOADH(0);
    STOREH();

    unsigned short* pw = p_s + wv * 16 * PS_STRIDE;
    unsigned short* xh = xh_s + wv * 16 * XH_STRIDE;

    // X_h A-fragments carried in NAMED registers (rule #20: no runtime indexing)
    bf16x8 ax0, ax1, ax2, ax3, ax4, ax5;

    #pragma unroll
    for (int h = 0; h < 6; ++h) {
        __syncthreads();                 // A: stage for head h visible
        if (h < 5) LOADH(h + 1);         // issue next head's loads early

        // bias+mask for this wave's 16 q-rows: lane needs bias[q=qbase+l16][k=nt*16+lhi*4+j]
        const float* bmh = bm_w + h * 4096;
        float4 bv[4];
        #pragma unroll
        for (int nt = 0; nt < 4; ++nt)
            bv[nt] = *(const float4*)&bmh[(qbase + l16) * 64 + nt * 16 + lhi * 4];

        // ---------- S^T = K Q^T (swapped: lane l16 holds q-column qbase+l16) ----------
        bf16x8 aq = *(const bf16x8*)&q_s[(qbase + l16) * QS_STRIDE + lhi * 8];
        float lg[4][4];   // lg[nt][j]: S[q=qbase+l16][k=nt*16+lhi*4+j] + bias
        #pragma unroll
        for (int nt = 0; nt < 4; ++nt) {
            bf16x8 bk = *(const bf16x8*)&k_s[(nt * 16 + l16) * QS_STRIDE + lhi * 8];
            f32x4 c = {0.f, 0.f, 0.f, 0.f};
            c = __builtin_amdgcn_mfma_f32_16x16x32_bf16(bk, aq, c, 0, 0, 0); // swapped operands
            lg[nt][0] = c[0] + bv[nt].x; lg[nt][1] = c[1] + bv[nt].y;
            lg[nt][2] = c[2] + bv[nt].z; lg[nt][3] = c[3] + bv[nt].w;
        }

        // ---------- lane-local softmax: 16 local values + 2-lane-hop reduce ----------
        float m = lg[0][0];
        #pragma unroll
        for (int nt = 0; nt < 4; ++nt)
            #pragma unroll
            for (int j = 0; j < 4; ++j) m = fmaxf(m, lg[nt][j]);
        m = fmaxf(m, __shfl_xor(m, 16, 64));
        m = fmaxf(m, __shfl_xor(m, 32, 64));
        float s = 0.f;
        #pragma unroll
        for (int nt = 0; nt < 4; ++nt)
            #pragma unroll
            for (int j = 0; j < 4; ++j) { lg[nt][j] = __expf(lg[nt][j] - m); s += lg[nt][j]; }
        s += __shfl_xor(s, 16, 64);
        s += __shfl_xor(s, 32, 64);
        float inv = __builtin_amdgcn_rcpf(s);

        // P (pre-normalized) -> own-wave strip: 4x packed ushort4, row q=l16
        #pragma unroll
        for (int nt = 0; nt < 4; ++nt) {
            ushort4 ph;
            ph.x = f2bf(lg[nt][0] * inv); ph.y = f2bf(lg[nt][1] * inv);
            ph.z = f2bf(lg[nt][2] * inv); ph.w = f2bf(lg[nt][3] * inv);
            *(ushort4*)&pw[l16 * PS_STRIDE + nt * 16 + lhi * 4] = ph;
        }

        // ---------- X_h = P V ----------
        f32x4 xo[2] = {{0.f,0.f,0.f,0.f},{0.f,0.f,0.f,0.f}};
        #pragma unroll
        for (int kk = 0; kk < 2; ++kk) {
            bf16x8 pa = *(const bf16x8*)&pw[l16 * PS_STRIDE + kk * 32 + lhi * 8];
            #pragma unroll
            for (int dt = 0; dt < 2; ++dt) {
                bf16x8 vb = *(const bf16x8*)&vT_s[(dt * 16 + l16) * VT_STRIDE + kk * 32 + lhi * 8];
                xo[dt] = __builtin_amdgcn_mfma_f32_16x16x32_bf16(pa, vb, xo[dt], 0, 0, 0);
            }
        }
        // X_h (C-layout) -> own-wave strip (A-layout round trip, same-wave ordering)
        #pragma unroll
        for (int j = 0; j < 4; ++j) {
            #pragma unroll
            for (int dt = 0; dt < 2; ++dt)
                xh[(lhi * 4 + j) * XH_STRIDE + dt * 16 + l16] = f2bf(xo[dt][j]);
        }
        // read back A-fragment into this head's NAMED register
        {
            bf16x8 axv = *(const bf16x8*)&xh[l16 * XH_STRIDE + lhi * 8];
            if (h == 0) ax0 = axv;
            else if (h == 1) ax1 = axv;
            else if (h == 2) ax2 = axv;
            else if (h == 3) ax3 = axv;
            else if (h == 4) ax4 = axv;
            else             ax5 = axv;
        }

        __syncthreads();                 // B: all waves done reading q/k/vT
        if (h < 5) STOREH();             // write next head's stage
    }
#undef LOADH
#undef STOREH

    // ---------- out = X @ W^T + bias (X entirely in registers) ----------
    f32x4 oacc[12];
    #pragma unroll
    for (int ct = 0; ct < 12; ++ct) oacc[ct] = (f32x4){0.f, 0.f, 0.f, 0.f};
    #pragma unroll
    for (int kk = 0; kk < 6; ++kk) {
        bf16x8 ax = (kk == 0) ? ax0 : (kk == 1) ? ax1 : (kk == 2) ? ax2
                  : (kk == 3) ? ax3 : (kk == 4) ? ax4 : ax5;
        #pragma unroll
        for (int ct = 0; ct < 12; ++ct) {
            bf16x8 bw = *(const bf16x8*)&wf[((kk * 12 + ct) * 64 + lane) * 8];
            oacc[ct] = __builtin_amdgcn_mfma_f32_16x16x32_bf16(ax, bw, oacc[ct], 0, 0, 0);
        }
    }
    float* outb = out + (size_t)b * 64 * 192;
    #pragma unroll
    for (int ct = 0; ct < 12; ++ct) {
        int co = ct * 16 + l16;
        float bias = proj_b[co];
        #pragma unroll
        for (int j = 0; j < 4; ++j) {
            int n = qbase + lhi * 4 + j;
            outb[n * 192 + co] = oacc[ct][j] + bias;
        }
    }
}

// ---------------- fallback (self-contained, used if ws too small) ----------------

#define XS_STRIDE 200
#define WS_STRIDE 40

__global__ __launch_bounds__(256)
void winattn_fused(const float* __restrict__ qkv,
                   const int* __restrict__ rpi32,
                   const float* __restrict__ mask,
                   const float* __restrict__ rpb_table,
                   const float* __restrict__ proj_w,
                   const float* __restrict__ proj_b,
                   float* __restrict__ out) {
    __shared__ __align__(16) unsigned short x_s[64 * XS_STRIDE];
    __shared__ __align__(16) unsigned short u_s[12032];
    __shared__ float rpb_s[225];
    __shared__ int rpi_is64_s;

    unsigned short* q_s  = u_s;
    unsigned short* k_s  = u_s + 2560;
    unsigned short* vT_s = u_s + 5120;
    unsigned short* p_s  = u_s + 7424;
    unsigned short* w_s  = u_s;

    const int tid  = threadIdx.x;
    const int b    = blockIdx.x;
    const int lane = tid & 63;
    const int wv   = tid >> 6;
    const int l16  = lane & 15;
    const int lhi  = lane >> 4;
    const int qbase = wv * 16;
    const float scale = 0.17677669529663687f;

    if (tid == 0) {
        int s = 0;
        #pragma unroll
        for (int i = 0; i < 16; ++i) s |= rpi32[2 * i + 1];
        rpi_is64_s = (s == 0) ? 1 : 0;
    }

    const float* maskw = mask + (size_t)(b & 63) * 4096;
    const float* qkv_b = qkv + (size_t)b * 64 * 576;

    for (int h = 0; h < 6; ++h) {
        for (int idx = tid; idx < 64 * 8; idx += 256) {
            int tok = idx >> 3, d = (idx & 7) << 2;
            const float4* base = (const float4*)(qkv_b + tok * 576 + h * 32 + d);
            float4 qv = base[0];
            float4 kv = base[48];
            float4 vv = base[96];
            ushort4 qh, kh;
            qh.x = f2bf(qv.x * scale); qh.y = f2bf(qv.y * scale);
            qh.z = f2bf(qv.z * scale); qh.w = f2bf(qv.w * scale);
            kh.x = f2bf(kv.x); kh.y = f2bf(kv.y); kh.z = f2bf(kv.z); kh.w = f2bf(kv.w);
            *(ushort4*)&q_s[tok * QS_STRIDE + d] = qh;
            *(ushort4*)&k_s[tok * QS_STRIDE + d] = kh;
            vT_s[(d + 0) * VT_STRIDE + tok] = f2bf(vv.x);
            vT_s[(d + 1) * VT_STRIDE + tok] = f2bf(vv.y);
            vT_s[(d + 2) * VT_STRIDE + tok] = f2bf(vv.z);
            vT_s[(d + 3) * VT_STRIDE + tok] = f2bf(vv.w);
        }
        if (tid < 225) rpb_s[tid] = rpb_table[tid * 6 + h];
        __syncthreads();
        const int is64 = rpi_is64_s;

        bf16x8 aq = *(const bf16x8*)&q_s[(qbase + l16) * QS_STRIDE + lhi * 8];
        float lg[4][4];
        #pragma unroll
        for (int nt = 0; nt < 4; ++nt) {
            bf16x8 bk = *(const bf16x8*)&k_s[(nt * 16 + l16) * QS_STRIDE + lhi * 8];
            f32x4 c = {0.f, 0.f, 0.f, 0.f};
            c = __builtin_amdgcn_mfma_f32_16x16x32_bf16(aq, bk, c, 0, 0, 0);
            #pragma unroll
            for (int j = 0; j < 4; ++j) lg[nt][j] = c[j];
        }
        #pragma unroll
        for (int nt = 0; nt < 4; ++nt) {
            int c = nt * 16 + l16;
            #pragma unroll
            for (int j = 0; j < 4; ++j) {
                int r = qbase + lhi * 4 + j;
                int e = r * 64 + c;
                int rv = is64 ? rpi32[2 * e] : rpi32[e];
                lg[nt][j] += rpb_s[rv] + maskw[e];
            }
        }
        float srow[4];
        float p[4][4];
        #pragma unroll
        for (int j = 0; j < 4; ++j) {
            float m = fmaxf(fmaxf(lg[0][j], lg[1][j]), fmaxf(lg[2][j], lg[3][j]));
            #pragma unroll
            for (int o = 1; o < 16; o <<= 1) m = fmaxf(m, __shfl_xor(m, o, 64));
            float s = 0.f;
            #pragma unroll
            for (int nt = 0; nt < 4; ++nt) { p[nt][j] = __expf(lg[nt][j] - m); s += p[nt][j]; }
            #pragma unroll
            for (int o = 1; o < 16; o <<= 1) s += __shfl_xor(s, o, 64);
            srow[j] = s;
        }
        __syncthreads();
        unsigned short* pw = p_s + wv * 16 * PS_STRIDE;
        #pragma unroll
        for (int nt = 0; nt < 4; ++nt)
            #pragma unroll
            for (int j = 0; j < 4; ++j)
                pw[(lhi * 4 + j) * PS_STRIDE + nt * 16 + l16] = f2bf(p[nt][j]);
        __syncthreads();

        f32x4 xo[2] = {{0.f,0.f,0.f,0.f},{0.f,0.f,0.f,0.f}};
        #pragma unroll
        for (int kk = 0; kk < 2; ++kk) {
            bf16x8 pa = *(const bf16x8*)&pw[l16 * PS_STRIDE + kk * 32 + lhi * 8];
            #pragma unroll
            for (int dt = 0; dt < 2; ++dt) {
                bf16x8 vb = *(const bf16x8*)&vT_s[(dt * 16 + l16) * VT_STRIDE + kk * 32 + lhi * 8];
                xo[dt] = __builtin_amdgcn_mfma_f32_16x16x32_bf16(pa, vb, xo[dt], 0, 0, 0);
            }
        }
        #pragma unroll
        for (int j = 0; j < 4; ++j) {
            float inv = 1.f / srow[j];
            int n = qbase + lhi * 4 + j;
            #pragma unroll
            for (int dt = 0; dt < 2; ++dt)
                x_s[n * XS_STRIDE + h * 32 + dt * 16 + l16] = f2bf(xo[dt][j] * inv);
        }
        __syncthreads();
    }

    f32x4 oacc[12];
    #pragma unroll
    for (int ct = 0; ct < 12; ++ct) oacc[ct] = (f32x4){0.f, 0.f, 0.f, 0.f};
    for (int kk = 0; kk < 6; ++kk) {
        for (int idx = tid; idx < 192 * 8; idx += 256) {
            int co = idx >> 3, d = (idx & 7) << 2;
            float4 wvv = *(const float4*)(proj_w + co * 192 + kk * 32 + d);
            ushort4 wh;
            wh.x = f2bf(wvv.x); wh.y = f2bf(wvv.y); wh.z = f2bf(wvv.z); wh.w = f2bf(wvv.w);
            *(ushort4*)&w_s[co * WS_STRIDE + d] = wh;
        }
        __syncthreads();
        bf16x8 ax = *(const bf16x8*)&x_s[(qbase + l16) * XS_STRIDE + kk * 32 + lhi * 8];
        #pragma unroll
        for (int ct = 0; ct < 12; ++ct) {
            bf16x8 bw = *(const bf16x8*)&w_s[(ct * 16 + l16) * WS_STRIDE + lhi * 8];
            oacc[ct] = __builtin_amdgcn_mfma_f32_16x16x32_bf16(ax, bw, oacc[ct], 0, 0, 0);
        }
        __syncthreads();
    }
    float* outb = out + (size_t)b * 64 * 192;
    #pragma unroll
    for (int ct = 0; ct < 12; ++ct) {
        int co = ct * 16 + l16;
        float bias = proj_b[co];
        #pragma unroll
        for (int j = 0; j < 4; ++j) {
            int n = qbase + lhi * 4 + j;
            outb[n * 192 + co] = oacc[ct][j] + bias;
        }
    }
}

extern "C" void kernel_launch(void* const* d_in, const int* in_sizes, int n_in,
                              void* d_out, int out_size, void* d_ws, size_t ws_size,
                              hipStream_t stream) {
    (void)in_sizes; (void)n_in; (void)out_size;
    const float* qkv       = (const float*)d_in[0];
    const int*   rpi       = (const int*)d_in[1];
    const float* mask      = (const float*)d_in[2];
    const float* rpb_table = (const float*)d_in[3];
    const float* proj_w    = (const float*)d_in[4];
    const float* proj_b    = (const float*)d_in[5];
    float* out = (float*)d_out;

    const size_t BM_BYTES = (size_t)64 * 6 * 4096 * sizeof(float);   // 6,291,456
    const size_t WF_BYTES = (size_t)36864 * sizeof(unsigned short);  // 73,728

    if (ws_size >= BM_BYTES + WF_BYTES) {
        float* bmp = (float*)d_ws;
        unsigned short* wfp = (unsigned short*)((char*)d_ws + BM_BYTES);
        prep_all<<<6144 + 144, 256, 0, stream>>>(rpi, mask, rpb_table, proj_w, bmp, wfp);
        winattn_fast<<<4096, 256, 0, stream>>>(qkv, bmp, wfp, proj_b, out);
    } else {
        winattn_fused<<<4096, 256, 0, stream>>>(qkv, rpi, mask, rpb_table, proj_w, proj_b, out);
    }
}

// Round 12
// 190.575 us; speedup vs baseline: 1.4492x; 1.0723x over previous
//
#include <hip/hip_runtime.h>
#include <stdint.h>

typedef __bf16 bf16x8 __attribute__((ext_vector_type(8)));
typedef float f32x4 __attribute__((ext_vector_type(4)));

// Native bf16 conversion (RNE): compiler emits v_cvt_pk_bf16_f32 on gfx950.
__device__ __forceinline__ unsigned short f2bf(float f) {
    union { __bf16 h; unsigned short u; } v;
    v.h = (__bf16)f;
    return v.u;
}

#define QS_STRIDE 40   // q/k 64x32 tiles, +8 pad
#define VT_STRIDE 72   // vT 32x64 tile, +8 pad
#define PS_STRIDE 72   // p 16x64 per-wave strip, +8 pad
#define XS_STRIDE 200  // x 64x192 tile, +8 pad

// ---------------- combined precompute kernel ----------------
// blocks [0,6144):  bm[(w*6+h)*4096 + r*64 + c] = mask[w][r][c] + rpb[rpi[r][c]][h]
// blocks [6144,6288): wf[((kk*12+ct)*64+lane)*8+e] = bf16(W[ct*16+(lane&15)][kk*32+(lane>>4)*8+e])
__global__ void prep_all(const int* __restrict__ rpi32,
                         const float* __restrict__ mask,
                         const float* __restrict__ rpb,
                         const float* __restrict__ proj_w,
                         float* __restrict__ bm,
                         unsigned short* __restrict__ wf) {
    int bid = blockIdx.x;
    int tid = threadIdx.x;
    if (bid < 6144) {
        __shared__ int is64_s;
        if (tid == 0) {
            int s = 0;
            #pragma unroll
            for (int i = 0; i < 16; ++i) s |= rpi32[2 * i + 1];
            is64_s = (s == 0);
        }
        __syncthreads();
        int g = bid * 256 + tid;              // < 64*6*4096
        int wh = g >> 12;                     // w*6+h
        int e  = g & 4095;                    // r*64 + c
        int h = wh % 6, w = wh / 6;
        int rv = is64_s ? rpi32[2 * e] : rpi32[e];
        bm[g] = mask[w * 4096 + e] + rpb[rv * 6 + h];
    } else {
        int g = (bid - 6144) * 256 + tid;     // < 36864
        int e = g & 7;
        int lane = (g >> 3) & 63;
        int kkct = g >> 9;
        int kk = kkct / 12, ct = kkct % 12;
        int co = ct * 16 + (lane & 15);
        int ki = kk * 32 + (lane >> 4) * 8 + e;
        wf[g] = f2bf(proj_w[co * 192 + ki]);
    }
}

// ------ fast fused kernel (R8 champion + bm prefetched one head ahead) ------

__global__ __launch_bounds__(256, 3)
void winattn_fast(const float* __restrict__ qkv,
                  const float* __restrict__ bm,
                  const unsigned short* __restrict__ wf,
                  const float* __restrict__ proj_b,
                  float* __restrict__ out) {
    __shared__ __align__(16) unsigned short x_s[64 * XS_STRIDE];      // 25600 B
    __shared__ __align__(16) unsigned short u_s[7424];                // 14848 B: q|k|vT
    __shared__ __align__(16) unsigned short p_s[4 * 16 * PS_STRIDE];  // 9216 B (own-wave strips)

    unsigned short* q_s  = u_s;          // [64][40]
    unsigned short* k_s  = u_s + 2560;   // [64][40]
    unsigned short* vT_s = u_s + 5120;   // [32][72]

    const int tid  = threadIdx.x;
    const int b    = blockIdx.x;
    const int lane = tid & 63;
    const int wv   = tid >> 6;
    const int l16  = lane & 15;
    const int lhi  = lane >> 4;
    const int qbase = wv * 16;
    const float scale = 0.17677669529663687f;

    const float* qkv_b = qkv + (size_t)b * 64 * 576;
    const float* bm_w  = bm + (size_t)(b & 63) * 6 * 4096;
    const float* bm_l  = bm_w + (qbase + l16) * 64 + lhi * 4;  // + h*4096 + nt*16 per use

    // staging geometry: thread covers (tokA, dA) and (tokB = tokA+32, dA)
    const int tokA = tid >> 3;
    const int dA   = (tid & 7) << 2;
    const float4* gA = (const float4*)(qkv_b + tokA * 576 + dA); // head h: +h*8 (f4), k:+48, v:+96
    const float4* gB = (const float4*)(qkv_b + (tokA + 32) * 576 + dA);

    float4 q0, k0, v0, q1, k1, v1;

#define LOADH(h_)  do { int o = (h_) * 8;                         \
        q0 = gA[o];      k0 = gA[o + 48]; v0 = gA[o + 96];        \
        q1 = gB[o];      k1 = gB[o + 48]; v1 = gB[o + 96]; } while (0)

#define STOREH() do {                                             \
        ushort4 qh, kh;                                           \
        qh.x = f2bf(q0.x * scale); qh.y = f2bf(q0.y * scale);     \
        qh.z = f2bf(q0.z * scale); qh.w = f2bf(q0.w * scale);     \
        kh.x = f2bf(k0.x); kh.y = f2bf(k0.y);                     \
        kh.z = f2bf(k0.z); kh.w = f2bf(k0.w);                     \
        *(ushort4*)&q_s[tokA * QS_STRIDE + dA] = qh;              \
        *(ushort4*)&k_s[tokA * QS_STRIDE + dA] = kh;              \
        vT_s[(dA + 0) * VT_STRIDE + tokA] = f2bf(v0.x);           \
        vT_s[(dA + 1) * VT_STRIDE + tokA] = f2bf(v0.y);           \
        vT_s[(dA + 2) * VT_STRIDE + tokA] = f2bf(v0.z);           \
        vT_s[(dA + 3) * VT_STRIDE + tokA] = f2bf(v0.w);           \
        qh.x = f2bf(q1.x * scale); qh.y = f2bf(q1.y * scale);     \
        qh.z = f2bf(q1.z * scale); qh.w = f2bf(q1.w * scale);     \
        kh.x = f2bf(k1.x); kh.y = f2bf(k1.y);                     \
        kh.z = f2bf(k1.z); kh.w = f2bf(k1.w);                     \
        *(ushort4*)&q_s[(tokA + 32) * QS_STRIDE + dA] = qh;       \
        *(ushort4*)&k_s[(tokA + 32) * QS_STRIDE + dA] = kh;       \
        vT_s[(dA + 0) * VT_STRIDE + tokA + 32] = f2bf(v1.x);      \
        vT_s[(dA + 1) * VT_STRIDE + tokA + 32] = f2bf(v1.y);      \
        vT_s[(dA + 2) * VT_STRIDE + tokA + 32] = f2bf(v1.z);      \
        vT_s[(dA + 3) * VT_STRIDE + tokA + 32] = f2bf(v1.w); } while (0)

    LOADH(0);
    STOREH();

    unsigned short* pw = p_s + wv * 16 * PS_STRIDE;

    // bias+mask prefetch: head-0 loads issued in the prologue (HBM/L3 latency
    // hides under the first barrier + fragment loads); each head issues h+1's.
    float4 bv[4], bvn[4];
    #pragma unroll
    for (int nt = 0; nt < 4; ++nt)
        bv[nt] = *(const float4*)&bm_l[nt * 16];

    for (int h = 0; h < 6; ++h) {
        __syncthreads();                 // A: stage for head h visible
        if (h < 5) {
            LOADH(h + 1);                // next head's qkv (consumed at STOREH after barrier B)
            #pragma unroll
            for (int nt = 0; nt < 4; ++nt)   // next head's bias (consumed next iteration)
                bvn[nt] = *(const float4*)&bm_l[(h + 1) * 4096 + nt * 16];
        }

        // ---------- S^T = K Q^T (swapped: lane l16 holds q-column qbase+l16) ----------
        bf16x8 aq = *(const bf16x8*)&q_s[(qbase + l16) * QS_STRIDE + lhi * 8];
        float lg[4][4];   // lg[nt][j]: S[q=qbase+l16][k=nt*16+lhi*4+j] + bias
        #pragma unroll
        for (int nt = 0; nt < 4; ++nt) {
            bf16x8 bk = *(const bf16x8*)&k_s[(nt * 16 + l16) * QS_STRIDE + lhi * 8];
            f32x4 c = {0.f, 0.f, 0.f, 0.f};
            c = __builtin_amdgcn_mfma_f32_16x16x32_bf16(bk, aq, c, 0, 0, 0); // swapped operands
            lg[nt][0] = c[0] + bv[nt].x; lg[nt][1] = c[1] + bv[nt].y;
            lg[nt][2] = c[2] + bv[nt].z; lg[nt][3] = c[3] + bv[nt].w;
        }

        // ---------- lane-local softmax: 16 local values + 2-lane-hop reduce ----------
        float m = lg[0][0];
        #pragma unroll
        for (int nt = 0; nt < 4; ++nt)
            #pragma unroll
            for (int j = 0; j < 4; ++j) m = fmaxf(m, lg[nt][j]);
        m = fmaxf(m, __shfl_xor(m, 16, 64));
        m = fmaxf(m, __shfl_xor(m, 32, 64));
        float s = 0.f;
        #pragma unroll
        for (int nt = 0; nt < 4; ++nt)
            #pragma unroll
            for (int j = 0; j < 4; ++j) { lg[nt][j] = __expf(lg[nt][j] - m); s += lg[nt][j]; }
        s += __shfl_xor(s, 16, 64);
        s += __shfl_xor(s, 32, 64);
        float inv = __builtin_amdgcn_rcpf(s);

        // P (pre-normalized) -> own-wave strip: 4x packed ushort4, row q=l16
        #pragma unroll
        for (int nt = 0; nt < 4; ++nt) {
            ushort4 ph;
            ph.x = f2bf(lg[nt][0] * inv); ph.y = f2bf(lg[nt][1] * inv);
            ph.z = f2bf(lg[nt][2] * inv); ph.w = f2bf(lg[nt][3] * inv);
            *(ushort4*)&pw[l16 * PS_STRIDE + nt * 16 + lhi * 4] = ph;
        }

        // ---------- X_h = P V ----------
        f32x4 xo[2] = {{0.f,0.f,0.f,0.f},{0.f,0.f,0.f,0.f}};
        #pragma unroll
        for (int kk = 0; kk < 2; ++kk) {
            bf16x8 pa = *(const bf16x8*)&pw[l16 * PS_STRIDE + kk * 32 + lhi * 8];
            #pragma unroll
            for (int dt = 0; dt < 2; ++dt) {
                bf16x8 vb = *(const bf16x8*)&vT_s[(dt * 16 + l16) * VT_STRIDE + kk * 32 + lhi * 8];
                xo[dt] = __builtin_amdgcn_mfma_f32_16x16x32_bf16(pa, vb, xo[dt], 0, 0, 0);
            }
        }
        // X_h (C-layout: row q=qbase+lhi*4+j, col d=dt*16+l16), already normalized
        #pragma unroll
        for (int j = 0; j < 4; ++j) {
            int n = qbase + lhi * 4 + j;
            #pragma unroll
            for (int dt = 0; dt < 2; ++dt)
                x_s[n * XS_STRIDE + h * 32 + dt * 16 + l16] = f2bf(xo[dt][j]);
        }

        __syncthreads();                 // B: all waves done reading q/k/vT
        if (h < 5) {
            STOREH();                    // write next head's stage
            #pragma unroll
            for (int nt = 0; nt < 4; ++nt) bv[nt] = bvn[nt];
        }
    }
#undef LOADH
#undef STOREH

    // ---------- out = X @ W^T + bias (x_s own-strip reads: no barrier) ----------
    f32x4 oacc[12];
    #pragma unroll
    for (int ct = 0; ct < 12; ++ct) oacc[ct] = (f32x4){0.f, 0.f, 0.f, 0.f};
    #pragma unroll
    for (int kk = 0; kk < 6; ++kk) {
        bf16x8 ax = *(const bf16x8*)&x_s[(qbase + l16) * XS_STRIDE + kk * 32 + lhi * 8];
        #pragma unroll
        for (int ct = 0; ct < 12; ++ct) {
            bf16x8 bw = *(const bf16x8*)&wf[((kk * 12 + ct) * 64 + lane) * 8];
            oacc[ct] = __builtin_amdgcn_mfma_f32_16x16x32_bf16(ax, bw, oacc[ct], 0, 0, 0);
        }
    }
    float* outb = out + (size_t)b * 64 * 192;
    #pragma unroll
    for (int ct = 0; ct < 12; ++ct) {
        int co = ct * 16 + l16;
        float bias = proj_b[co];
        #pragma unroll
        for (int j = 0; j < 4; ++j) {
            int n = qbase + lhi * 4 + j;
            outb[n * 192 + co] = oacc[ct][j] + bias;
        }
    }
}

// ---------------- fallback (self-contained, used if ws too small) ----------------

#define WS_STRIDE 40

__global__ __launch_bounds__(256)
void winattn_fused(const float* __restrict__ qkv,
                   const int* __restrict__ rpi32,
                   const float* __restrict__ mask,
                   const float* __restrict__ rpb_table,
                   const float* __restrict__ proj_w,
                   const float* __restrict__ proj_b,
                   float* __restrict__ out) {
    __shared__ __align__(16) unsigned short x_s[64 * XS_STRIDE];
    __shared__ __align__(16) unsigned short u_s[12032];
    __shared__ float rpb_s[225];
    __shared__ int rpi_is64_s;

    unsigned short* q_s  = u_s;
    unsigned short* k_s  = u_s + 2560;
    unsigned short* vT_s = u_s + 5120;
    unsigned short* p_s  = u_s + 7424;
    unsigned short* w_s  = u_s;

    const int tid  = threadIdx.x;
    const int b    = blockIdx.x;
    const int lane = tid & 63;
    const int wv   = tid >> 6;
    const int l16  = lane & 15;
    const int lhi  = lane >> 4;
    const int qbase = wv * 16;
    const float scale = 0.17677669529663687f;

    if (tid == 0) {
        int s = 0;
        #pragma unroll
        for (int i = 0; i < 16; ++i) s |= rpi32[2 * i + 1];
        rpi_is64_s = (s == 0) ? 1 : 0;
    }

    const float* maskw = mask + (size_t)(b & 63) * 4096;
    const float* qkv_b = qkv + (size_t)b * 64 * 576;

    for (int h = 0; h < 6; ++h) {
        for (int idx = tid; idx < 64 * 8; idx += 256) {
            int tok = idx >> 3, d = (idx & 7) << 2;
            const float4* base = (const float4*)(qkv_b + tok * 576 + h * 32 + d);
            float4 qv = base[0];
            float4 kv = base[48];
            float4 vv = base[96];
            ushort4 qh, kh;
            qh.x = f2bf(qv.x * scale); qh.y = f2bf(qv.y * scale);
            qh.z = f2bf(qv.z * scale); qh.w = f2bf(qv.w * scale);
            kh.x = f2bf(kv.x); kh.y = f2bf(kv.y); kh.z = f2bf(kv.z); kh.w = f2bf(kv.w);
            *(ushort4*)&q_s[tok * QS_STRIDE + d] = qh;
            *(ushort4*)&k_s[tok * QS_STRIDE + d] = kh;
            vT_s[(d + 0) * VT_STRIDE + tok] = f2bf(vv.x);
            vT_s[(d + 1) * VT_STRIDE + tok] = f2bf(vv.y);
            vT_s[(d + 2) * VT_STRIDE + tok] = f2bf(vv.z);
            vT_s[(d + 3) * VT_STRIDE + tok] = f2bf(vv.w);
        }
        if (tid < 225) rpb_s[tid] = rpb_table[tid * 6 + h];
        __syncthreads();
        const int is64 = rpi_is64_s;

        bf16x8 aq = *(const bf16x8*)&q_s[(qbase + l16) * QS_STRIDE + lhi * 8];
        float lg[4][4];
        #pragma unroll
        for (int nt = 0; nt < 4; ++nt) {
            bf16x8 bk = *(const bf16x8*)&k_s[(nt * 16 + l16) * QS_STRIDE + lhi * 8];
            f32x4 c = {0.f, 0.f, 0.f, 0.f};
            c = __builtin_amdgcn_mfma_f32_16x16x32_bf16(aq, bk, c, 0, 0, 0);
            #pragma unroll
            for (int j = 0; j < 4; ++j) lg[nt][j] = c[j];
        }
        #pragma unroll
        for (int nt = 0; nt < 4; ++nt) {
            int c = nt * 16 + l16;
            #pragma unroll
            for (int j = 0; j < 4; ++j) {
                int r = qbase + lhi * 4 + j;
                int e = r * 64 + c;
                int rv = is64 ? rpi32[2 * e] : rpi32[e];
                lg[nt][j] += rpb_s[rv] + maskw[e];
            }
        }
        float srow[4];
        float p[4][4];
        #pragma unroll
        for (int j = 0; j < 4; ++j) {
            float m = fmaxf(fmaxf(lg[0][j], lg[1][j]), fmaxf(lg[2][j], lg[3][j]));
            #pragma unroll
            for (int o = 1; o < 16; o <<= 1) m = fmaxf(m, __shfl_xor(m, o, 64));
            float s = 0.f;
            #pragma unroll
            for (int nt = 0; nt < 4; ++nt) { p[nt][j] = __expf(lg[nt][j] - m); s += p[nt][j]; }
            #pragma unroll
            for (int o = 1; o < 16; o <<= 1) s += __shfl_xor(s, o, 64);
            srow[j] = s;
        }
        __syncthreads();
        unsigned short* pw = p_s + wv * 16 * PS_STRIDE;
        #pragma unroll
        for (int nt = 0; nt < 4; ++nt)
            #pragma unroll
            for (int j = 0; j < 4; ++j)
                pw[(lhi * 4 + j) * PS_STRIDE + nt * 16 + l16] = f2bf(p[nt][j]);
        __syncthreads();

        f32x4 xo[2] = {{0.f,0.f,0.f,0.f},{0.f,0.f,0.f,0.f}};
        #pragma unroll
        for (int kk = 0; kk < 2; ++kk) {
            bf16x8 pa = *(const bf16x8*)&pw[l16 * PS_STRIDE + kk * 32 + lhi * 8];
            #pragma unroll
            for (int dt = 0; dt < 2; ++dt) {
                bf16x8 vb = *(const bf16x8*)&vT_s[(dt * 16 + l16) * VT_STRIDE + kk * 32 + lhi * 8];
                xo[dt] = __builtin_amdgcn_mfma_f32_16x16x32_bf16(pa, vb, xo[dt], 0, 0, 0);
            }
        }
        #pragma unroll
        for (int j = 0; j < 4; ++j) {
            float inv = 1.f / srow[j];
            int n = qbase + lhi * 4 + j;
            #pragma unroll
            for (int dt = 0; dt < 2; ++dt)
                x_s[n * XS_STRIDE + h * 32 + dt * 16 + l16] = f2bf(xo[dt][j] * inv);
        }
        __syncthreads();
    }

    f32x4 oacc[12];
    #pragma unroll
    for (int ct = 0; ct < 12; ++ct) oacc[ct] = (f32x4){0.f, 0.f, 0.f, 0.f};
    for (int kk = 0; kk < 6; ++kk) {
        for (int idx = tid; idx < 192 * 8; idx += 256) {
            int co = idx >> 3, d = (idx & 7) << 2;
            float4 wvv = *(const float4*)(proj_w + co * 192 + kk * 32 + d);
            ushort4 wh;
            wh.x = f2bf(wvv.x); wh.y = f2bf(wvv.y); wh.z = f2bf(wvv.z); wh.w = f2bf(wvv.w);
            *(ushort4*)&w_s[co * WS_STRIDE + d] = wh;
        }
        __syncthreads();
        bf16x8 ax = *(const bf16x8*)&x_s[(qbase + l16) * XS_STRIDE + kk * 32 + lhi * 8];
        #pragma unroll
        for (int ct = 0; ct < 12; ++ct) {
            bf16x8 bw = *(const bf16x8*)&w_s[(ct * 16 + l16) * WS_STRIDE + lhi * 8];
            oacc[ct] = __builtin_amdgcn_mfma_f32_16x16x32_bf16(ax, bw, oacc[ct], 0, 0, 0);
        }
        __syncthreads();
    }
    float* outb = out + (size_t)b * 64 * 192;
    #pragma unroll
    for (int ct = 0; ct < 12; ++ct) {
        int co = ct * 16 + l16;
        float bias = proj_b[co];
        #pragma unroll
        for (int j = 0; j < 4; ++j) {
            int n = qbase + lhi * 4 + j;
            outb[n * 192 + co] = oacc[ct][j] + bias;
        }
    }
}

extern "C" void kernel_launch(void* const* d_in, const int* in_sizes, int n_in,
                              void* d_out, int out_size, void* d_ws, size_t ws_size,
                              hipStream_t stream) {
    (void)in_sizes; (void)n_in; (void)out_size;
    const float* qkv       = (const float*)d_in[0];
    const int*   rpi       = (const int*)d_in[1];
    const float* mask      = (const float*)d_in[2];
    const float* rpb_table = (const float*)d_in[3];
    const float* proj_w    = (const float*)d_in[4];
    const float* proj_b    = (const float*)d_in[5];
    float* out = (float*)d_out;

    const size_t BM_BYTES = (size_t)64 * 6 * 4096 * sizeof(float);   // 6,291,456
    const size_t WF_BYTES = (size_t)36864 * sizeof(unsigned short);  // 73,728

    if (ws_size >= BM_BYTES + WF_BYTES) {
        float* bmp = (float*)d_ws;
        unsigned short* wfp = (unsigned short*)((char*)d_ws + BM_BYTES);
        prep_all<<<6144 + 144, 256, 0, stream>>>(rpi, mask, rpb_table, proj_w, bmp, wfp);
        winattn_fast<<<4096, 256, 0, stream>>>(qkv, bmp, wfp, proj_b, out);
    } else {
        winattn_fused<<<4096, 256, 0, stream>>>(qkv, rpi, mask, rpb_table, proj_w, proj_b, out);
    }
}

// Round 13
// 186.637 us; speedup vs baseline: 1.4798x; 1.0211x over previous
//
#include <hip/hip_runtime.h>
#include <stdint.h>

typedef __bf16 bf16x8 __attribute__((ext_vector_type(8)));
typedef float f32x4 __attribute__((ext_vector_type(4)));

// Native bf16 conversion (RNE): compiler emits v_cvt_pk_bf16_f32 on gfx950.
__device__ __forceinline__ unsigned short f2bf(float f) {
    union { __bf16 h; unsigned short u; } v;
    v.h = (__bf16)f;
    return v.u;
}
__device__ __forceinline__ float bf2f(unsigned short u) {
    union { uint32_t u32; float f; } v;
    v.u32 = ((uint32_t)u) << 16;
    return v.f;
}

#define QS_STRIDE 40   // q/k 64x32 tiles, +8 pad
#define VT_STRIDE 72   // vT 32x64 tile, +8 pad
#define PS_STRIDE 72   // p 16x64 per-wave strip, +8 pad
#define XS_STRIDE 200  // x 64x192 tile, +8 pad

// ---------------- combined precompute kernel ----------------
// blocks [0,96):   rpbT[h*4096 + r*64 + c] = bf16(rpb[rpi[r][c]][h])   (49 KB, L2-hot everywhere)
// blocks [96,240): wf[((kk*12+ct)*64+lane)*8+e] = bf16(W[ct*16+(lane&15)][kk*32+(lane>>4)*8+e])
__global__ void prep_all(const int* __restrict__ rpi32,
                         const float* __restrict__ rpb,
                         const float* __restrict__ proj_w,
                         unsigned short* __restrict__ rpbT,
                         unsigned short* __restrict__ wf) {
    int bid = blockIdx.x;
    int tid = threadIdx.x;
    if (bid < 96) {
        __shared__ int is64_s;
        if (tid == 0) {
            int s = 0;
            #pragma unroll
            for (int i = 0; i < 16; ++i) s |= rpi32[2 * i + 1];
            is64_s = (s == 0);
        }
        __syncthreads();
        int g = bid * 256 + tid;              // < 6*4096
        int e = g & 4095;                     // r*64 + c
        int h = g >> 12;
        int rv = is64_s ? rpi32[2 * e] : rpi32[e];
        rpbT[g] = f2bf(rpb[rv * 6 + h]);
    } else {
        int g = (bid - 96) * 256 + tid;       // < 36864
        int e = g & 7;
        int lane = (g >> 3) & 63;
        int kkct = g >> 9;
        int kk = kkct / 12, ct = kkct % 12;
        int co = ct * 16 + (lane & 15);
        int ki = kk * 32 + (lane >> 4) * 8 + e;
        wf[g] = f2bf(proj_w[co * 192 + ki]);
    }
}

// --- fast fused kernel: R12 champion with bm split into mask (once/block) + rpbT (L2-hot bf16) ---

__global__ __launch_bounds__(256, 3)
void winattn_fast(const float* __restrict__ qkv,
                  const float* __restrict__ mask,
                  const unsigned short* __restrict__ rpbT,
                  const unsigned short* __restrict__ wf,
                  const float* __restrict__ proj_b,
                  float* __restrict__ out) {
    __shared__ __align__(16) unsigned short x_s[64 * XS_STRIDE];      // 25600 B
    __shared__ __align__(16) unsigned short u_s[7424];                // 14848 B: q|k|vT
    __shared__ __align__(16) unsigned short p_s[4 * 16 * PS_STRIDE];  // 9216 B (own-wave strips)

    unsigned short* q_s  = u_s;          // [64][40]
    unsigned short* k_s  = u_s + 2560;   // [64][40]
    unsigned short* vT_s = u_s + 5120;   // [32][72]

    const int tid  = threadIdx.x;
    const int b    = blockIdx.x;
    const int lane = tid & 63;
    const int wv   = tid >> 6;
    const int l16  = lane & 15;
    const int lhi  = lane >> 4;
    const int qbase = wv * 16;
    const float scale = 0.17677669529663687f;

    const float* qkv_b = qkv + (size_t)b * 64 * 576;
    // per-lane bias bases: row q = qbase+l16, cols nt*16 + lhi*4 .. +3
    const float* mask_l = mask + (size_t)(b & 63) * 4096 + (qbase + l16) * 64 + lhi * 4;
    const unsigned short* rpb_l = rpbT + (qbase + l16) * 64 + lhi * 4;  // + h*4096 + nt*16

    // staging geometry: thread covers (tokA, dA) and (tokB = tokA+32, dA)
    const int tokA = tid >> 3;
    const int dA   = (tid & 7) << 2;
    const float4* gA = (const float4*)(qkv_b + tokA * 576 + dA); // head h: +h*8 (f4), k:+48, v:+96
    const float4* gB = (const float4*)(qkv_b + (tokA + 32) * 576 + dA);

    float4 q0, k0, v0, q1, k1, v1;

#define LOADH(h_)  do { int o = (h_) * 8;                         \
        q0 = gA[o];      k0 = gA[o + 48]; v0 = gA[o + 96];        \
        q1 = gB[o];      k1 = gB[o + 48]; v1 = gB[o + 96]; } while (0)

#define STOREH() do {                                             \
        ushort4 qh, kh;                                           \
        qh.x = f2bf(q0.x * scale); qh.y = f2bf(q0.y * scale);     \
        qh.z = f2bf(q0.z * scale); qh.w = f2bf(q0.w * scale);     \
        kh.x = f2bf(k0.x); kh.y = f2bf(k0.y);                     \
        kh.z = f2bf(k0.z); kh.w = f2bf(k0.w);                     \
        *(ushort4*)&q_s[tokA * QS_STRIDE + dA] = qh;              \
        *(ushort4*)&k_s[tokA * QS_STRIDE + dA] = kh;              \
        vT_s[(dA + 0) * VT_STRIDE + tokA] = f2bf(v0.x);           \
        vT_s[(dA + 1) * VT_STRIDE + tokA] = f2bf(v0.y);           \
        vT_s[(dA + 2) * VT_STRIDE + tokA] = f2bf(v0.z);           \
        vT_s[(dA + 3) * VT_STRIDE + tokA] = f2bf(v0.w);           \
        qh.x = f2bf(q1.x * scale); qh.y = f2bf(q1.y * scale);     \
        qh.z = f2bf(q1.z * scale); qh.w = f2bf(q1.w * scale);     \
        kh.x = f2bf(k1.x); kh.y = f2bf(k1.y);                     \
        kh.z = f2bf(k1.z); kh.w = f2bf(k1.w);                     \
        *(ushort4*)&q_s[(tokA + 32) * QS_STRIDE + dA] = qh;       \
        *(ushort4*)&k_s[(tokA + 32) * QS_STRIDE + dA] = kh;       \
        vT_s[(dA + 0) * VT_STRIDE + tokA + 32] = f2bf(v1.x);      \
        vT_s[(dA + 1) * VT_STRIDE + tokA + 32] = f2bf(v1.y);      \
        vT_s[(dA + 2) * VT_STRIDE + tokA + 32] = f2bf(v1.z);      \
        vT_s[(dA + 3) * VT_STRIDE + tokA + 32] = f2bf(v1.w); } while (0)

    LOADH(0);
    STOREH();

    unsigned short* pw = p_s + wv * 16 * PS_STRIDE;

    // mask part: loaded ONCE per block (head-independent), lives in 16 VGPRs.
    float4 mv[4];
    #pragma unroll
    for (int nt = 0; nt < 4; ++nt)
        mv[nt] = *(const float4*)&mask_l[nt * 16];
    // rpb part: tiny shared bf16 table (L2-hot); prefetched one head ahead.
    ushort4 rb[4], rbn[4];
    #pragma unroll
    for (int nt = 0; nt < 4; ++nt)
        rb[nt] = *(const ushort4*)&rpb_l[nt * 16];

    for (int h = 0; h < 6; ++h) {
        __syncthreads();                 // A: stage for head h visible
        if (h < 5) {
            LOADH(h + 1);                // next head's qkv (consumed at STOREH after barrier B)
            #pragma unroll
            for (int nt = 0; nt < 4; ++nt)   // next head's rpb slice (consumed next iteration)
                rbn[nt] = *(const ushort4*)&rpb_l[(h + 1) * 4096 + nt * 16];
        }

        // bias = mask (persistent regs) + rpb (bf16->f32)
        float bias[4][4];
        #pragma unroll
        for (int nt = 0; nt < 4; ++nt) {
            bias[nt][0] = mv[nt].x + bf2f(rb[nt].x);
            bias[nt][1] = mv[nt].y + bf2f(rb[nt].y);
            bias[nt][2] = mv[nt].z + bf2f(rb[nt].z);
            bias[nt][3] = mv[nt].w + bf2f(rb[nt].w);
        }

        // ---------- S^T = K Q^T (swapped: lane l16 holds q-column qbase+l16) ----------
        bf16x8 aq = *(const bf16x8*)&q_s[(qbase + l16) * QS_STRIDE + lhi * 8];
        float lg[4][4];   // lg[nt][j]: S[q=qbase+l16][k=nt*16+lhi*4+j] + bias
        #pragma unroll
        for (int nt = 0; nt < 4; ++nt) {
            bf16x8 bk = *(const bf16x8*)&k_s[(nt * 16 + l16) * QS_STRIDE + lhi * 8];
            f32x4 c = {0.f, 0.f, 0.f, 0.f};
            c = __builtin_amdgcn_mfma_f32_16x16x32_bf16(bk, aq, c, 0, 0, 0); // swapped operands
            lg[nt][0] = c[0] + bias[nt][0]; lg[nt][1] = c[1] + bias[nt][1];
            lg[nt][2] = c[2] + bias[nt][2]; lg[nt][3] = c[3] + bias[nt][3];
        }

        // ---------- lane-local softmax: 16 local values + 2-lane-hop reduce ----------
        float m = lg[0][0];
        #pragma unroll
        for (int nt = 0; nt < 4; ++nt)
            #pragma unroll
            for (int j = 0; j < 4; ++j) m = fmaxf(m, lg[nt][j]);
        m = fmaxf(m, __shfl_xor(m, 16, 64));
        m = fmaxf(m, __shfl_xor(m, 32, 64));
        float s = 0.f;
        #pragma unroll
        for (int nt = 0; nt < 4; ++nt)
            #pragma unroll
            for (int j = 0; j < 4; ++j) { lg[nt][j] = __expf(lg[nt][j] - m); s += lg[nt][j]; }
        s += __shfl_xor(s, 16, 64);
        s += __shfl_xor(s, 32, 64);
        float inv = __builtin_amdgcn_rcpf(s);

        // P (pre-normalized) -> own-wave strip: 4x packed ushort4, row q=l16
        #pragma unroll
        for (int nt = 0; nt < 4; ++nt) {
            ushort4 ph;
            ph.x = f2bf(lg[nt][0] * inv); ph.y = f2bf(lg[nt][1] * inv);
            ph.z = f2bf(lg[nt][2] * inv); ph.w = f2bf(lg[nt][3] * inv);
            *(ushort4*)&pw[l16 * PS_STRIDE + nt * 16 + lhi * 4] = ph;
        }

        // ---------- X_h = P V ----------
        f32x4 xo[2] = {{0.f,0.f,0.f,0.f},{0.f,0.f,0.f,0.f}};
        #pragma unroll
        for (int kk = 0; kk < 2; ++kk) {
            bf16x8 pa = *(const bf16x8*)&pw[l16 * PS_STRIDE + kk * 32 + lhi * 8];
            #pragma unroll
            for (int dt = 0; dt < 2; ++dt) {
                bf16x8 vb = *(const bf16x8*)&vT_s[(dt * 16 + l16) * VT_STRIDE + kk * 32 + lhi * 8];
                xo[dt] = __builtin_amdgcn_mfma_f32_16x16x32_bf16(pa, vb, xo[dt], 0, 0, 0);
            }
        }
        // X_h (C-layout: row q=qbase+lhi*4+j, col d=dt*16+l16), already normalized
        #pragma unroll
        for (int j = 0; j < 4; ++j) {
            int n = qbase + lhi * 4 + j;
            #pragma unroll
            for (int dt = 0; dt < 2; ++dt)
                x_s[n * XS_STRIDE + h * 32 + dt * 16 + l16] = f2bf(xo[dt][j]);
        }

        __syncthreads();                 // B: all waves done reading q/k/vT
        if (h < 5) {
            STOREH();                    // write next head's stage
            #pragma unroll
            for (int nt = 0; nt < 4; ++nt) rb[nt] = rbn[nt];
        }
    }
#undef LOADH
#undef STOREH

    // ---------- out = X @ W^T + bias (x_s own-strip reads: no barrier) ----------
    f32x4 oacc[12];
    #pragma unroll
    for (int ct = 0; ct < 12; ++ct) oacc[ct] = (f32x4){0.f, 0.f, 0.f, 0.f};
    #pragma unroll
    for (int kk = 0; kk < 6; ++kk) {
        bf16x8 ax = *(const bf16x8*)&x_s[(qbase + l16) * XS_STRIDE + kk * 32 + lhi * 8];
        #pragma unroll
        for (int ct = 0; ct < 12; ++ct) {
            bf16x8 bw = *(const bf16x8*)&wf[((kk * 12 + ct) * 64 + lane) * 8];
            oacc[ct] = __builtin_amdgcn_mfma_f32_16x16x32_bf16(ax, bw, oacc[ct], 0, 0, 0);
        }
    }
    float* outb = out + (size_t)b * 64 * 192;
    #pragma unroll
    for (int ct = 0; ct < 12; ++ct) {
        int co = ct * 16 + l16;
        float bias = proj_b[co];
        #pragma unroll
        for (int j = 0; j < 4; ++j) {
            int n = qbase + lhi * 4 + j;
            outb[n * 192 + co] = oacc[ct][j] + bias;
        }
    }
}

// ---------------- fallback (self-contained, used if ws too small) ----------------

#define WS_STRIDE 40

__global__ __launch_bounds__(256)
void winattn_fused(const float* __restrict__ qkv,
                   const int* __restrict__ rpi32,
                   const float* __restrict__ mask,
                   const float* __restrict__ rpb_table,
                   const float* __restrict__ proj_w,
                   const float* __restrict__ proj_b,
                   float* __restrict__ out) {
    __shared__ __align__(16) unsigned short x_s[64 * XS_STRIDE];
    __shared__ __align__(16) unsigned short u_s[12032];
    __shared__ float rpb_s[225];
    __shared__ int rpi_is64_s;

    unsigned short* q_s  = u_s;
    unsigned short* k_s  = u_s + 2560;
    unsigned short* vT_s = u_s + 5120;
    unsigned short* p_s  = u_s + 7424;
    unsigned short* w_s  = u_s;

    const int tid  = threadIdx.x;
    const int b    = blockIdx.x;
    const int lane = tid & 63;
    const int wv   = tid >> 6;
    const int l16  = lane & 15;
    const int lhi  = lane >> 4;
    const int qbase = wv * 16;
    const float scale = 0.17677669529663687f;

    if (tid == 0) {
        int s = 0;
        #pragma unroll
        for (int i = 0; i < 16; ++i) s |= rpi32[2 * i + 1];
        rpi_is64_s = (s == 0) ? 1 : 0;
    }

    const float* maskw = mask + (size_t)(b & 63) * 4096;
    const float* qkv_b = qkv + (size_t)b * 64 * 576;

    for (int h = 0; h < 6; ++h) {
        for (int idx = tid; idx < 64 * 8; idx += 256) {
            int tok = idx >> 3, d = (idx & 7) << 2;
            const float4* base = (const float4*)(qkv_b + tok * 576 + h * 32 + d);
            float4 qv = base[0];
            float4 kv = base[48];
            float4 vv = base[96];
            ushort4 qh, kh;
            qh.x = f2bf(qv.x * scale); qh.y = f2bf(qv.y * scale);
            qh.z = f2bf(qv.z * scale); qh.w = f2bf(qv.w * scale);
            kh.x = f2bf(kv.x); kh.y = f2bf(kv.y); kh.z = f2bf(kv.z); kh.w = f2bf(kv.w);
            *(ushort4*)&q_s[tok * QS_STRIDE + d] = qh;
            *(ushort4*)&k_s[tok * QS_STRIDE + d] = kh;
            vT_s[(d + 0) * VT_STRIDE + tok] = f2bf(vv.x);
            vT_s[(d + 1) * VT_STRIDE + tok] = f2bf(vv.y);
            vT_s[(d + 2) * VT_STRIDE + tok] = f2bf(vv.z);
            vT_s[(d + 3) * VT_STRIDE + tok] = f2bf(vv.w);
        }
        if (tid < 225) rpb_s[tid] = rpb_table[tid * 6 + h];
        __syncthreads();
        const int is64 = rpi_is64_s;

        bf16x8 aq = *(const bf16x8*)&q_s[(qbase + l16) * QS_STRIDE + lhi * 8];
        float lg[4][4];
        #pragma unroll
        for (int nt = 0; nt < 4; ++nt) {
            bf16x8 bk = *(const bf16x8*)&k_s[(nt * 16 + l16) * QS_STRIDE + lhi * 8];
            f32x4 c = {0.f, 0.f, 0.f, 0.f};
            c = __builtin_amdgcn_mfma_f32_16x16x32_bf16(aq, bk, c, 0, 0, 0);
            #pragma unroll
            for (int j = 0; j < 4; ++j) lg[nt][j] = c[j];
        }
        #pragma unroll
        for (int nt = 0; nt < 4; ++nt) {
            int c = nt * 16 + l16;
            #pragma unroll
            for (int j = 0; j < 4; ++j) {
                int r = qbase + lhi * 4 + j;
                int e = r * 64 + c;
                int rv = is64 ? rpi32[2 * e] : rpi32[e];
                lg[nt][j] += rpb_s[rv] + maskw[e];
            }
        }
        float srow[4];
        float p[4][4];
        #pragma unroll
        for (int j = 0; j < 4; ++j) {
            float m = fmaxf(fmaxf(lg[0][j], lg[1][j]), fmaxf(lg[2][j], lg[3][j]));
            #pragma unroll
            for (int o = 1; o < 16; o <<= 1) m = fmaxf(m, __shfl_xor(m, o, 64));
            float s = 0.f;
            #pragma unroll
            for (int nt = 0; nt < 4; ++nt) { p[nt][j] = __expf(lg[nt][j] - m); s += p[nt][j]; }
            #pragma unroll
            for (int o = 1; o < 16; o <<= 1) s += __shfl_xor(s, o, 64);
            srow[j] = s;
        }
        __syncthreads();
        unsigned short* pw = p_s + wv * 16 * PS_STRIDE;
        #pragma unroll
        for (int nt = 0; nt < 4; ++nt)
            #pragma unroll
            for (int j = 0; j < 4; ++j)
                pw[(lhi * 4 + j) * PS_STRIDE + nt * 16 + l16] = f2bf(p[nt][j]);
        __syncthreads();

        f32x4 xo[2] = {{0.f,0.f,0.f,0.f},{0.f,0.f,0.f,0.f}};
        #pragma unroll
        for (int kk = 0; kk < 2; ++kk) {
            bf16x8 pa = *(const bf16x8*)&pw[l16 * PS_STRIDE + kk * 32 + lhi * 8];
            #pragma unroll
            for (int dt = 0; dt < 2; ++dt) {
                bf16x8 vb = *(const bf16x8*)&vT_s[(dt * 16 + l16) * VT_STRIDE + kk * 32 + lhi * 8];
                xo[dt] = __builtin_amdgcn_mfma_f32_16x16x32_bf16(pa, vb, xo[dt], 0, 0, 0);
            }
        }
        #pragma unroll
        for (int j = 0; j < 4; ++j) {
            float inv = 1.f / srow[j];
            int n = qbase + lhi * 4 + j;
            #pragma unroll
            for (int dt = 0; dt < 2; ++dt)
                x_s[n * XS_STRIDE + h * 32 + dt * 16 + l16] = f2bf(xo[dt][j] * inv);
        }
        __syncthreads();
    }

    f32x4 oacc[12];
    #pragma unroll
    for (int ct = 0; ct < 12; ++ct) oacc[ct] = (f32x4){0.f, 0.f, 0.f, 0.f};
    for (int kk = 0; kk < 6; ++kk) {
        for (int idx = tid; idx < 192 * 8; idx += 256) {
            int co = idx >> 3, d = (idx & 7) << 2;
            float4 wvv = *(const float4*)(proj_w + co * 192 + kk * 32 + d);
            ushort4 wh;
            wh.x = f2bf(wvv.x); wh.y = f2bf(wvv.y); wh.z = f2bf(wvv.z); wh.w = f2bf(wvv.w);
            *(ushort4*)&w_s[co * WS_STRIDE + d] = wh;
        }
        __syncthreads();
        bf16x8 ax = *(const bf16x8*)&x_s[(qbase + l16) * XS_STRIDE + kk * 32 + lhi * 8];
        #pragma unroll
        for (int ct = 0; ct < 12; ++ct) {
            bf16x8 bw = *(const bf16x8*)&w_s[(ct * 16 + l16) * WS_STRIDE + lhi * 8];
            oacc[ct] = __builtin_amdgcn_mfma_f32_16x16x32_bf16(ax, bw, oacc[ct], 0, 0, 0);
        }
        __syncthreads();
    }
    float* outb = out + (size_t)b * 64 * 192;
    #pragma unroll
    for (int ct = 0; ct < 12; ++ct) {
        int co = ct * 16 + l16;
        float bias = proj_b[co];
        #pragma unroll
        for (int j = 0; j < 4; ++j) {
            int n = qbase + lhi * 4 + j;
            outb[n * 192 + co] = oacc[ct][j] + bias;
        }
    }
}

extern "C" void kernel_launch(void* const* d_in, const int* in_sizes, int n_in,
                              void* d_out, int out_size, void* d_ws, size_t ws_size,
                              hipStream_t stream) {
    (void)in_sizes; (void)n_in; (void)out_size;
    const float* qkv       = (const float*)d_in[0];
    const int*   rpi       = (const int*)d_in[1];
    const float* mask      = (const float*)d_in[2];
    const float* rpb_table = (const float*)d_in[3];
    const float* proj_w    = (const float*)d_in[4];
    const float* proj_b    = (const float*)d_in[5];
    float* out = (float*)d_out;

    const size_t RT_BYTES = (size_t)6 * 4096 * sizeof(unsigned short);  // 49,152
    const size_t WF_BYTES = (size_t)36864 * sizeof(unsigned short);     // 73,728

    if (ws_size >= RT_BYTES + WF_BYTES) {
        unsigned short* rpbT = (unsigned short*)d_ws;
        unsigned short* wfp  = (unsigned short*)((char*)d_ws + RT_BYTES);
        prep_all<<<240, 256, 0, stream>>>(rpi, rpb_table, proj_w, rpbT, wfp);
        winattn_fast<<<4096, 256, 0, stream>>>(qkv, mask, rpbT, wfp, proj_b, out);
    } else {
        winattn_fused<<<4096, 256, 0, stream>>>(qkv, rpi, mask, rpb_table, proj_w, proj_b, out);
    }
}